// Round 17
// baseline (382.786 us; speedup 1.0000x reference)
//
#include <hip/hip_runtime.h>
#include <hip/hip_bf16.h>

// ---- problem constants ----
#define SEM_DIM   256
#define CODEBOOK  8192
#define B_        8
#define T_        4096
#define D_        292
#define NCH       37
#define EPSV      1e-5f
#define NSP       4            // codebook splits
#define KAPPA     2.05e-3f     // >= 2^-9 deterministic fp16-dot error coeff
#define D0        0.01f        // absolute slack for fp32 epilogue rounding
#define CAP       128
#define QMAX      768          // 3 KB queue (rare overflow -> direct global)

typedef unsigned short u16;
typedef float v4f __attribute__((ext_vector_type(4)));
typedef _Float16 v8h __attribute__((ext_vector_type(8)));
typedef _Float16 v4h __attribute__((ext_vector_type(4)));

constexpr int ROWS = B_ * T_;                 // 32768
// d_out as flat scratch until final writers run. Scratch spans [0, 7.43M fl);
// finalize/fsq/gather overwrite the full 10.78M-fl output afterwards.
constexpr size_t OFF_XT   = 0;                // fp16[32768*256] = 4,194,304 fl
constexpr size_t OFF_ET   = 4194304;          // fp16[8192*256]  = 1,048,576 fl
constexpr size_t OFF_E2G  = 5242880;          // e2f[8192] + gf[8192]
constexpr size_t OFF_X2   = 5259264;          // f32[32768]
constexpr size_t OFF_CNT  = 5292032;          // i32[32768]
constexpr size_t OFF_CAND = 5324800;          // u16[32768*128] -> 7,421,952
constexpr size_t RECON_OFF = 1212416;

__device__ __forceinline__ u16 h16bits(float v) {
    _Float16 h = (_Float16)v;
    return *(u16*)&h;
}

// ---- kernel 1: Et = fp16(clamp(es/max(cu,eps))) panel-transposed; e2f/gf;
//      also zero-inits cnt and x2 (folded former init_kernel) ----
__global__ __launch_bounds__(256) void prep_emb_kernel(
    const float* __restrict__ es, const float* __restrict__ cu,
    u16* __restrict__ Et, float* __restrict__ e2f, float* __restrict__ gf,
    int* __restrict__ cnt, float* __restrict__ x2)
{
    int c = blockIdx.x;
    int d = threadIdx.x;
    if (c < 128)                  cnt[c * 256 + d] = 0;
    else if (c < 256)             x2[(c - 128) * 256 + d] = 0.f;

    float denom = fmaxf(cu[c], EPSV);
    float v = es[(size_t)c * SEM_DIM + d] / denom;   // IEEE div, matches ref
    float vc = fminf(fmaxf(v, -60000.f), 60000.f);   // fp16-overflow guard

    __shared__ u16 hbuf[256];
    hbuf[d] = h16bits(vc);

    float s = v * v;
    #pragma unroll
    for (int m = 32; m >= 1; m >>= 1) s += __shfl_xor(s, m);
    __shared__ float red[4];
    int lane = d & 63, w = d >> 6;
    if (lane == 0) red[w] = s;
    __syncthreads();

    if (d < 32) {
        // panel-transposed: byte = (c>>6)*32768 + chunk*1024 + (c&63)*16
        uint4 pk = *(const uint4*)&hbuf[d * 8];
        size_t byt = (size_t)(c >> 6) * 32768 + (size_t)d * 1024 + (size_t)(c & 63) * 16;
        *(uint4*)((char*)Et + byt) = pk;
    }
    if (d == 0) {
        float e2 = red[0] + red[1] + red[2] + red[3];
        e2f[c] = e2;
        gf[c]  = KAPPA * sqrtf(e2);
    }
}

// ---- kernel 2: x[:, :256, :] -> Xt (fp16, MFMA-fragment order) + x2 ----
__global__ __launch_bounds__(256) void prep_x_kernel(
    const float* __restrict__ x, u16* __restrict__ Xt, float* __restrict__ x2)
{
    __shared__ float tile[64][65];
    int bidx = blockIdx.x;            // 8 * 64 * 4
    int dc = bidx & 3;
    int tc = (bidx >> 2) & 63;
    int b  = bidx >> 8;
    int d0 = dc * 64, t0 = tc * 64;
    int tx = threadIdx.x & 63;
    int dq = threadIdx.x >> 6;

    float part = 0.f;
    #pragma unroll
    for (int i = 0; i < 16; i++) {
        int d = dq * 16 + i;
        float v = x[((size_t)b * D_ + d0 + d) * T_ + t0 + tx];
        tile[d][tx] = v;
        part = fmaf(v, v, part);
    }
    atomicAdd(&x2[b * T_ + t0 + tx], part);
    __syncthreads();

    #pragma unroll
    for (int j = 0; j < 2; j++) {
        int lin = threadIdx.x * 2 + j;      // 0..511
        int tr  = lin >> 3;
        int ch  = lin & 7;
        unsigned w[4];
        #pragma unroll
        for (int p = 0; p < 4; p++) {
            float v0 = tile[ch * 8 + p * 2 + 0][tr];
            float v1 = tile[ch * 8 + p * 2 + 1][tr];
            w[p] = (unsigned)h16bits(v0) | ((unsigned)h16bits(v1) << 16);
        }
        int row = b * T_ + t0 + tr;
        int R = row >> 4, l15 = row & 15;
        int k8 = d0 / 8 + ch;
        int ks = k8 >> 2, l4 = k8 & 3;
        size_t byt = (size_t)((R * 8 + ks) * 4 + l4) * 256 + (size_t)l15 * 16;
        *(uint4*)((char*)Xt + byt) = make_uint4(w[0], w[1], w[2], w[3]);
    }
}

// ---- kernel 3: fp16 MFMA GEMM, 3-buffer counted-vmcnt pipeline (loop is
//      vmem-clean: only stage gll ops count), raw barriers, setprio around
//      MFMA, group emission test. ----
#define GBM 256
#define NTT (CODEBOOK / NSP / 32)             // 64 tiles of 32 codes

__global__ __launch_bounds__(512, 4) void gemm_emit_kernel(
    const u16* __restrict__ Xt, const u16* __restrict__ Et,
    const float* __restrict__ e2f, const float* __restrict__ gf,
    const float* __restrict__ x2,
    int* __restrict__ cnt, u16* __restrict__ cand)
{
    __shared__ u16 Bs[3][8192];               // 3 x 16 KB code tiles
    __shared__ float e2s[2048];               // 8 KB exact e2
    __shared__ _Float16 gs16[2048];           // 4 KB g (upward-rounded)
    __shared__ unsigned qbuf[QMAX];           // 3 KB
    __shared__ int qn;
    int tid  = threadIdx.x;
    int lane = tid & 63, wid = tid >> 6;      // 8 waves, m32 each
    int l15 = lane & 15, l4 = lane >> 4;
    int mblk = blockIdx.x >> 2, split = blockIdx.x & 3;
    int m0 = mblk * GBM;
    int cbase = split * (CODEBOOK / NSP);
    if (tid == 0) qn = 0;

    // stage score tables once (margin keeps fp16 g >= true g -> bounds sound)
    {
        int c4 = tid * 4;
        float4 e4 = *(const float4*)&e2f[cbase + c4];
        float4 g4 = *(const float4*)&gf[cbase + c4];
        *(float4*)&e2s[c4] = e4;
        v4h gh = { (_Float16)(g4.x * 1.0005f), (_Float16)(g4.y * 1.0005f),
                   (_Float16)(g4.z * 1.0005f), (_Float16)(g4.w * 1.0005f) };
        *(v4h*)&gs16[c4] = gh;
    }

    // x fragments resident (B-operand): m = m0 + wid*32 + mfm*16 + l15
    v8h aX[2][8];
    #pragma unroll
    for (int mfm = 0; mfm < 2; mfm++) {
        int Rb = (m0 + wid * 32 + mfm * 16) >> 4;
        #pragma unroll
        for (int ks = 0; ks < 8; ks++) {
            size_t byt = (size_t)((Rb * 8 + ks) * 4 + l4) * 256 + (size_t)l15 * 16;
            aX[mfm][ks] = *(const v8h*)((const char*)Xt + byt);
        }
    }

    float sxv[2], rvL[2];
    #pragma unroll
    for (int mfm = 0; mfm < 2; mfm++) {
        sxv[mfm] = sqrtf(x2[m0 + wid * 32 + mfm * 16 + l15]);
        rvL[mfm] = 3.4e38f;
    }

    v4f acc[2][2];                            // [mfc(code-half)][mfm(m-half)]
    #pragma unroll
    for (int a = 0; a < 2; a++)
        #pragma unroll
        for (int b = 0; b < 2; b++)
            acc[a][b] = (v4f){0.f, 0.f, 0.f, 0.f};

    // stage one 16 KB tile: 512 thr x 2 gll x 16B (the ONLY loop vmem ops)
    auto stage = [&](int nt, int buf) {
        const char* src = (const char*)Et
            + (size_t)(split * 32 + (nt >> 1)) * 32768 + (size_t)(nt & 1) * 512;
        #pragma unroll
        for (int j = 0; j < 2; j++) {
            int dofs = wid * 2048 + j * 1024 + lane * 16;
            int q = dofs >> 9;
            int o = (dofs >> 4) & 31;
            __builtin_amdgcn_global_load_lds(
                (const __attribute__((address_space(1))) unsigned*)(src + q * 1024 + o * 16),
                (__attribute__((address_space(3))) unsigned*)((char*)&Bs[buf][0] + dofs),
                16, 0, 0);
        }
    };

    stage(0, 0);
    stage(1, 1);

    for (int t = 0; t < NTT; ++t) {
        // counted wait: stage(t)'s ops retire (FIFO); stage(t+1) stays in flight
        if (t < NTT - 1) asm volatile("s_waitcnt vmcnt(2)" ::: "memory");
        else             asm volatile("s_waitcnt vmcnt(0)" ::: "memory");
        __builtin_amdgcn_s_barrier();
        asm volatile("" ::: "memory");
        if (t + 2 < NTT) stage(t + 2, (t + 2) % 3);   // a full tile of slack

        const char* bp = (const char*)&Bs[t % 3][0];
        __builtin_amdgcn_s_setprio(1);
        #pragma unroll
        for (int ks = 0; ks < 8; ks++) {
            int cofs = (ks * 4 + l4) * 512 + l15 * 16;
            v8h bC0 = *(const v8h*)(bp + cofs);
            v8h bC1 = *(const v8h*)(bp + cofs + 256);
            #pragma unroll
            for (int mfm = 0; mfm < 2; mfm++) {
                acc[0][mfm] = __builtin_amdgcn_mfma_f32_16x16x32_f16(
                    bC0, aX[mfm][ks], acc[0][mfm], 0, 0, 0);
                acc[1][mfm] = __builtin_amdgcn_mfma_f32_16x16x32_f16(
                    bC1, aX[mfm][ks], acc[1][mfm], 0, 0, 0);
            }
        }
        __builtin_amdgcn_s_setprio(0);

        // epilogue: lane owns codes c0 + mfc*16 + l4*4 + rr for m-col l15
        int c0  = cbase + t * 32;
        int clb = t * 32 + l4 * 4;
        float4 e2q0 = *(const float4*)&e2s[clb];
        float4 e2q1 = *(const float4*)&e2s[clb + 16];
        v4h gh0 = *(const v4h*)&gs16[clb];
        v4h gh1 = *(const v4h*)&gs16[clb + 16];
        float e2a[2][4] = {{e2q0.x, e2q0.y, e2q0.z, e2q0.w},
                           {e2q1.x, e2q1.y, e2q1.z, e2q1.w}};
        float ga[2][4]  = {{(float)gh0[0], (float)gh0[1], (float)gh0[2], (float)gh0[3]},
                           {(float)gh1[0], (float)gh1[1], (float)gh1[2], (float)gh1[3]}};

        #pragma unroll
        for (int mfm = 0; mfm < 2; mfm++) {
            float sx = sxv[mfm];
            float om = 3.4e38f, umin = 3.4e38f;
            float u[2][4];
            #pragma unroll
            for (int mfc = 0; mfc < 2; mfc++)
                #pragma unroll
                for (int rr = 0; rr < 4; rr++) {
                    float s = fmaf(-2.f, acc[mfc][mfm][rr], e2a[mfc][rr]);
                    om = fminf(om, fmaf(sx, ga[mfc][rr], s));
                    float uu = fmaf(-sx, ga[mfc][rr], s);
                    u[mfc][rr] = uu;
                    umin = fminf(umin, uu);
                }
            om = fminf(om, __shfl_xor(om, 16));
            om = fminf(om, __shfl_xor(om, 32));
            float rv = fminf(rvL[mfm], om);
            rvL[mfm] = rv;
            float th = rv + D0;
            if (umin <= th) {                 // group test: usually no lane passes
                int lrow = wid * 32 + mfm * 16 + l15;
                #pragma unroll
                for (int mfc = 0; mfc < 2; mfc++)
                    #pragma unroll
                    for (int rr = 0; rr < 4; rr++) {
                        if (u[mfc][rr] <= th) {
                            unsigned pk = ((unsigned)lrow << 13)
                                        | (unsigned)(c0 + mfc * 16 + l4 * 4 + rr);
                            int p = atomicAdd(&qn, 1);
                            if (p < QMAX) qbuf[p] = pk;
                            else {
                                int row = m0 + lrow;
                                int q = atomicAdd(&cnt[row], 1);
                                if (q < CAP) cand[(size_t)row * CAP + q] = (u16)(pk & 8191);
                            }
                        }
                    }
            }
        }
        #pragma unroll
        for (int a = 0; a < 2; a++)
            #pragma unroll
            for (int b = 0; b < 2; b++)
                acc[a][b] = (v4f){0.f, 0.f, 0.f, 0.f};
    }

    // flush LDS emission queue to global candidate lists
    __syncthreads();
    int n = qn; if (n > QMAX) n = QMAX;
    for (int i = tid; i < n; i += 512) {
        unsigned pk = qbuf[i];
        int row = m0 + (pk >> 13);
        int q = atomicAdd(&cnt[row], 1);
        if (q < CAP) cand[(size_t)row * CAP + q] = (u16)(pk & 8191);
    }
}

// ---- kernel 4: exact fp32 rescore, wave-per-row, div hoisted out of the
//      k-loop (1 div/candidate); wave-parallel scan fallback ----
__global__ __launch_bounds__(1024) void finalize_kernel(
    const int* __restrict__ cnt, const u16* __restrict__ cand,
    const float* __restrict__ x, const float* __restrict__ es,
    const float* __restrict__ cu, const float* __restrict__ e2f,
    float* __restrict__ out)
{
    int r = (blockIdx.x * 1024 + threadIdx.x) >> 6;  // one wave per row
    int lane = threadIdx.x & 63;
    int b = r >> 12, t = r & 4095;
    int n = cnt[r];

    float xv[4];
    #pragma unroll
    for (int j = 0; j < 4; j++)
        xv[j] = x[((size_t)b * D_ + lane + j * 64) * T_ + t];

    float best_s = 3.4e38f; int best_i = 0x7FFFFFFF;
    if (n <= CAP) {
        for (int p = 0; p < n; p++) {
            int c = (int)cand[(size_t)r * CAP + p];
            float partial = 0.f;
            #pragma unroll
            for (int j = 0; j < 4; j++)
                partial = fmaf(xv[j], es[(size_t)c * SEM_DIM + lane + j * 64], partial);
            #pragma unroll
            for (int m = 32; m >= 1; m >>= 1) partial += __shfl_xor(partial, m);
            float sc = fmaf(-2.0f / fmaxf(cu[c], EPSV), partial, e2f[c]);
            if (sc < best_s || (sc == best_s && c < best_i)) { best_s = sc; best_i = c; }
        }
    } else {
        // overflow fallback: exact wave-parallel scan of all codes
        for (int c = 0; c < CODEBOOK; c++) {
            float partial = 0.f;
            #pragma unroll
            for (int j = 0; j < 4; j++)
                partial = fmaf(xv[j], es[(size_t)c * SEM_DIM + lane + j * 64], partial);
            #pragma unroll
            for (int m = 32; m >= 1; m <<= 1) partial += __shfl_xor(partial, m);
            float sc = fmaf(-2.0f / fmaxf(cu[c], EPSV), partial, e2f[c]);
            if (sc < best_s) { best_s = sc; best_i = c; }
        }
    }
    if (lane == 0) out[(size_t)b * NCH * T_ + t] = (float)best_i;
}

// ---- kernel 5: FSQ codes + ac recon ----
__global__ __launch_bounds__(256) void fsq_kernel(
    const float* __restrict__ x, float* __restrict__ out)
{
    int e = blockIdx.x * 256 + threadIdx.x;
    int t = e & 4095;
    int rest = e >> 12;
    int j = rest % 36;
    int b = rest / 36;
    float v = x[(size_t)b * D_ * T_ + (size_t)(SEM_DIM + j) * T_ + t];
    float a = tanhf(v);
    float code = rintf((a + 1.0f) * 10.0f);
    out[(size_t)b * NCH * T_ + (size_t)(1 + j) * T_ + t] = code;
    out[RECON_OFF + (size_t)b * D_ * T_ + (size_t)(SEM_DIM + j) * T_ + t]
        = code * 0.1f - 1.0f;
}

// ---- kernel 6: recon sem gather ----
__global__ __launch_bounds__(256) void gather_kernel(
    const float* __restrict__ es, const float* __restrict__ cu,
    const float* __restrict__ codes, float* __restrict__ out)
{
    int bid = blockIdx.x;
    int b  = bid >> 6;
    int tc = bid & 63;
    int t  = tc * 64 + (threadIdx.x & 63);
    int w  = threadIdx.x >> 6;

    int c = (int)codes[(size_t)b * NCH * T_ + t];
    float denom = fmaxf(cu[c], EPSV);
    const float* erow = es + (size_t)c * SEM_DIM;
    float* orow = out + RECON_OFF + (size_t)b * D_ * T_ + t;

    #pragma unroll
    for (int i = 0; i < 16; i++) {
        int d = w * 64 + i * 4;
        float4 ev = *(const float4*)(erow + d);
        orow[(size_t)(d + 0) * T_] = ev.x / denom;
        orow[(size_t)(d + 1) * T_] = ev.y / denom;
        orow[(size_t)(d + 2) * T_] = ev.z / denom;
        orow[(size_t)(d + 3) * T_] = ev.w / denom;
    }
}

extern "C" void kernel_launch(void* const* d_in, const int* in_sizes, int n_in,
                              void* d_out, int out_size, void* d_ws, size_t ws_size,
                              hipStream_t stream)
{
    const float* x  = (const float*)d_in[0];
    const float* es = (const float*)d_in[1];
    const float* cu = (const float*)d_in[2];
    float* out = (float*)d_out;

    u16*   Xt   = (u16*)(out + OFF_XT);
    u16*   Et   = (u16*)(out + OFF_ET);
    float* e2f  = out + OFF_E2G;
    float* gf   = out + OFF_E2G + 8192;
    float* x2   = out + OFF_X2;
    int*   cnt  = (int*)(out + OFF_CNT);
    u16*   cand = (u16*)(out + OFF_CAND);

    prep_emb_kernel<<<CODEBOOK, 256, 0, stream>>>(es, cu, Et, e2f, gf, cnt, x2);
    prep_x_kernel<<<B_ * 64 * 4, 256, 0, stream>>>(x, Xt, x2);

    gemm_emit_kernel<<<(ROWS / GBM) * NSP, 512, 0, stream>>>(
        Xt, Et, e2f, gf, x2, cnt, cand);

    finalize_kernel<<<ROWS / 16, 1024, 0, stream>>>(cnt, cand, x, es, cu, e2f, out);

    fsq_kernel<<<(B_ * 36 * T_) / 256, 256, 0, stream>>>(x, out);

    gather_kernel<<<B_ * (T_ / 64), 256, 0, stream>>>(es, cu, out, out);
}

// Round 18
// 289.673 us; speedup vs baseline: 1.3214x; 1.3214x over previous
//
#include <hip/hip_runtime.h>
#include <hip/hip_bf16.h>

// ---- problem constants ----
#define SEM_DIM   256
#define CODEBOOK  8192
#define B_        8
#define T_        4096
#define D_        292
#define NCH       37
#define EPSV      1e-5f
#define NSP       4            // codebook splits
#define KAPPA     2.05e-3f     // >= 2^-9 deterministic fp16-dot error coeff
#define D0        0.01f        // absolute slack for fp32 epilogue rounding
#define CAP       128
#define QMAX      1536         // 6 KB queue -> 55.8 KB LDS -> exactly 2 blocks/CU

typedef unsigned short u16;
typedef float v4f __attribute__((ext_vector_type(4)));
typedef _Float16 v8h __attribute__((ext_vector_type(8)));

constexpr int ROWS = B_ * T_;                 // 32768
// d_out as flat scratch until final writers run. Scratch spans [0, 7.43M fl);
// finalize/tail overwrite the full 10.78M-fl output afterwards.
constexpr size_t OFF_XT   = 0;                // fp16[32768*256] = 4,194,304 fl
constexpr size_t OFF_ET   = 4194304;          // fp16[8192*256]  = 1,048,576 fl
constexpr size_t OFF_E2G  = 5242880;          // e2f[8192] + gf[8192]
constexpr size_t OFF_X2   = 5259264;          // f32[32768]
constexpr size_t OFF_CNT  = 5292032;          // i32[32768]
constexpr size_t OFF_CAND = 5324800;          // u16[32768*128] -> 7,421,952
constexpr size_t RECON_OFF = 1212416;

__device__ __forceinline__ u16 h16bits(float v) {
    _Float16 h = (_Float16)v;
    return *(u16*)&h;
}

// ---- kernel 1: Et = fp16(clamp(es/max(cu,eps))) panel-transposed; e2f/gf;
//      also zero-inits cnt and x2 (folded init) ----
__global__ __launch_bounds__(256) void prep_emb_kernel(
    const float* __restrict__ es, const float* __restrict__ cu,
    u16* __restrict__ Et, float* __restrict__ e2f, float* __restrict__ gf,
    int* __restrict__ cnt, float* __restrict__ x2)
{
    int c = blockIdx.x;
    int d = threadIdx.x;
    if (c < 128)       cnt[c * 256 + d] = 0;
    else if (c < 256)  x2[(c - 128) * 256 + d] = 0.f;

    float denom = fmaxf(cu[c], EPSV);
    float v = es[(size_t)c * SEM_DIM + d] / denom;   // IEEE div, matches ref
    float vc = fminf(fmaxf(v, -60000.f), 60000.f);   // fp16-overflow guard

    __shared__ u16 hbuf[256];
    hbuf[d] = h16bits(vc);

    float s = v * v;
    #pragma unroll
    for (int m = 32; m >= 1; m >>= 1) s += __shfl_xor(s, m);
    __shared__ float red[4];
    int lane = d & 63, w = d >> 6;
    if (lane == 0) red[w] = s;
    __syncthreads();

    if (d < 32) {
        // panel-transposed: byte = (c>>6)*32768 + chunk*1024 + (c&63)*16
        uint4 pk = *(const uint4*)&hbuf[d * 8];
        size_t byt = (size_t)(c >> 6) * 32768 + (size_t)d * 1024 + (size_t)(c & 63) * 16;
        *(uint4*)((char*)Et + byt) = pk;
    }
    if (d == 0) {
        float e2 = red[0] + red[1] + red[2] + red[3];
        e2f[c] = e2;
        gf[c]  = KAPPA * sqrtf(e2);
    }
}

// ---- kernel 2: x[:, :256, :] -> Xt (fp16, MFMA-fragment order) + x2 ----
__global__ __launch_bounds__(256) void prep_x_kernel(
    const float* __restrict__ x, u16* __restrict__ Xt, float* __restrict__ x2)
{
    __shared__ float tile[64][65];
    int bidx = blockIdx.x;            // 8 * 64 * 4
    int dc = bidx & 3;
    int tc = (bidx >> 2) & 63;
    int b  = bidx >> 8;
    int d0 = dc * 64, t0 = tc * 64;
    int tx = threadIdx.x & 63;
    int dq = threadIdx.x >> 6;

    float part = 0.f;
    #pragma unroll
    for (int i = 0; i < 16; i++) {
        int d = dq * 16 + i;
        float v = x[((size_t)b * D_ + d0 + d) * T_ + t0 + tx];
        tile[d][tx] = v;
        part = fmaf(v, v, part);
    }
    atomicAdd(&x2[b * T_ + t0 + tx], part);
    __syncthreads();

    #pragma unroll
    for (int j = 0; j < 2; j++) {
        int lin = threadIdx.x * 2 + j;      // 0..511
        int tr  = lin >> 3;
        int ch  = lin & 7;
        unsigned w[4];
        #pragma unroll
        for (int p = 0; p < 4; p++) {
            float v0 = tile[ch * 8 + p * 2 + 0][tr];
            float v1 = tile[ch * 8 + p * 2 + 1][tr];
            w[p] = (unsigned)h16bits(v0) | ((unsigned)h16bits(v1) << 16);
        }
        int row = b * T_ + t0 + tr;
        int R = row >> 4, l15 = row & 15;
        int k8 = d0 / 8 + ch;
        int ks = k8 >> 2, l4 = k8 & 3;
        size_t byt = (size_t)((R * 8 + ks) * 4 + l4) * 256 + (size_t)l15 * 16;
        *(uint4*)((char*)Xt + byt) = make_uint4(w[0], w[1], w[2], w[3]);
    }
}

// ---- kernel 3: fp16 MFMA GEMM (R16-exact: swapped operands, m32/wave,
//      8-wave blocks, NSP=4, 55.8 KB LDS -> even 2 blocks/CU). ----
#define GBM 256
#define NTT (CODEBOOK / NSP / 32)             // 64 tiles of 32 codes

__global__ __launch_bounds__(512, 4) void gemm_emit_kernel(
    const u16* __restrict__ Xt, const u16* __restrict__ Et,
    const float* __restrict__ e2f, const float* __restrict__ gf,
    const float* __restrict__ x2,
    int* __restrict__ cnt, u16* __restrict__ cand)
{
    __shared__ u16 Bs[2][8192];               // 2 x 16 KB code tiles
    __shared__ float e2s[2048], gs[2048];     // split-local score tables
    __shared__ unsigned qbuf[QMAX];           // 6 KB
    __shared__ int qn;
    int tid  = threadIdx.x;
    int lane = tid & 63, wid = tid >> 6;      // 8 waves, m32 each
    int l15 = lane & 15, l4 = lane >> 4;
    int mblk = blockIdx.x >> 2, split = blockIdx.x & 3;
    int m0 = mblk * GBM;
    int cbase = split * (CODEBOOK / NSP);
    if (tid == 0) qn = 0;

    // stage e2/g tables once (512 thr x 4 floats each)
    {
        int c4 = tid * 4;
        *(float4*)&e2s[c4] = *(const float4*)&e2f[cbase + c4];
        *(float4*)&gs[c4]  = *(const float4*)&gf[cbase + c4];
    }

    // x fragments resident (B-operand): m = m0 + wid*32 + mfm*16 + l15
    v8h aX[2][8];
    #pragma unroll
    for (int mfm = 0; mfm < 2; mfm++) {
        int Rb = (m0 + wid * 32 + mfm * 16) >> 4;
        #pragma unroll
        for (int ks = 0; ks < 8; ks++) {
            size_t byt = (size_t)((Rb * 8 + ks) * 4 + l4) * 256 + (size_t)l15 * 16;
            aX[mfm][ks] = *(const v8h*)((const char*)Xt + byt);
        }
    }

    float sxv[2], rvL[2];
    #pragma unroll
    for (int mfm = 0; mfm < 2; mfm++) {
        sxv[mfm] = sqrtf(x2[m0 + wid * 32 + mfm * 16 + l15]);
        rvL[mfm] = 3.4e38f;
    }

    v4f acc[2][2];                            // [mfc(code-half)][mfm(m-half)]
    #pragma unroll
    for (int a = 0; a < 2; a++)
        #pragma unroll
        for (int b = 0; b < 2; b++)
            acc[a][b] = (v4f){0.f, 0.f, 0.f, 0.f};

    // stage one 16 KB tile (32 codes x 256 K): 512 thr x 2 x 16B
    auto stage = [&](int nt, int buf) {
        const char* src = (const char*)Et
            + (size_t)(split * 32 + (nt >> 1)) * 32768 + (size_t)(nt & 1) * 512;
        #pragma unroll
        for (int j = 0; j < 2; j++) {
            int dofs = wid * 2048 + j * 1024 + lane * 16;
            int q = dofs >> 9;
            int o = (dofs >> 4) & 31;
            __builtin_amdgcn_global_load_lds(
                (const __attribute__((address_space(1))) unsigned*)(src + q * 1024 + o * 16),
                (__attribute__((address_space(3))) unsigned*)((char*)&Bs[buf][0] + dofs),
                16, 0, 0);
        }
    };

    stage(0, 0);

    for (int t = 0; t < NTT; ++t) {
        int buf = t & 1;
        __syncthreads();                      // stage(t) landed; prev reads done
        if (t + 1 < NTT) stage(t + 1, buf ^ 1);

        const char* bp = (const char*)&Bs[buf][0];
        #pragma unroll
        for (int ks = 0; ks < 8; ks++) {
            int cofs = (ks * 4 + l4) * 512 + l15 * 16;
            v8h bC0 = *(const v8h*)(bp + cofs);
            v8h bC1 = *(const v8h*)(bp + cofs + 256);
            #pragma unroll
            for (int mfm = 0; mfm < 2; mfm++) {
                acc[0][mfm] = __builtin_amdgcn_mfma_f32_16x16x32_f16(
                    bC0, aX[mfm][ks], acc[0][mfm], 0, 0, 0);
                acc[1][mfm] = __builtin_amdgcn_mfma_f32_16x16x32_f16(
                    bC1, aX[mfm][ks], acc[1][mfm], 0, 0, 0);
            }
        }

        // epilogue: lane owns codes c0 + mfc*16 + l4*4 + rr for m-col l15
        int c0  = cbase + t * 32;
        int clb = t * 32 + l4 * 4;
        float4 e2q0 = *(const float4*)&e2s[clb];
        float4 e2q1 = *(const float4*)&e2s[clb + 16];
        float4 gq0  = *(const float4*)&gs[clb];
        float4 gq1  = *(const float4*)&gs[clb + 16];
        float e2a[2][4] = {{e2q0.x, e2q0.y, e2q0.z, e2q0.w},
                           {e2q1.x, e2q1.y, e2q1.z, e2q1.w}};
        float ga[2][4]  = {{gq0.x, gq0.y, gq0.z, gq0.w},
                           {gq1.x, gq1.y, gq1.z, gq1.w}};

        #pragma unroll
        for (int mfm = 0; mfm < 2; mfm++) {
            float sx = sxv[mfm];
            float om = 3.4e38f;
            float u[2][4];
            #pragma unroll
            for (int mfc = 0; mfc < 2; mfc++)
                #pragma unroll
                for (int rr = 0; rr < 4; rr++) {
                    float s = fmaf(-2.f, acc[mfc][mfm][rr], e2a[mfc][rr]);
                    om = fminf(om, fmaf(sx, ga[mfc][rr], s));
                    u[mfc][rr] = fmaf(-sx, ga[mfc][rr], s);
                }
            om = fminf(om, __shfl_xor(om, 16));
            om = fminf(om, __shfl_xor(om, 32));
            float rv = fminf(rvL[mfm], om);
            rvL[mfm] = rv;
            float th = rv + D0;
            int lrow = wid * 32 + mfm * 16 + l15;
            #pragma unroll
            for (int mfc = 0; mfc < 2; mfc++)
                #pragma unroll
                for (int rr = 0; rr < 4; rr++) {
                    if (u[mfc][rr] <= th) {   // rare
                        unsigned pk = ((unsigned)lrow << 13)
                                    | (unsigned)(c0 + mfc * 16 + l4 * 4 + rr);
                        int p = atomicAdd(&qn, 1);
                        if (p < QMAX) qbuf[p] = pk;
                        else {
                            int row = m0 + lrow;
                            int q = atomicAdd(&cnt[row], 1);
                            if (q < CAP) cand[(size_t)row * CAP + q] = (u16)(pk & 8191);
                        }
                    }
                }
        }
        #pragma unroll
        for (int a = 0; a < 2; a++)
            #pragma unroll
            for (int b = 0; b < 2; b++)
                acc[a][b] = (v4f){0.f, 0.f, 0.f, 0.f};
    }

    // flush LDS emission queue to global candidate lists
    __syncthreads();
    int n = qn; if (n > QMAX) n = QMAX;
    for (int i = tid; i < n; i += 512) {
        unsigned pk = qbuf[i];
        int row = m0 + (pk >> 13);
        int q = atomicAdd(&cnt[row], 1);
        if (q < CAP) cand[(size_t)row * CAP + q] = (u16)(pk & 8191);
    }
}

// ---- kernel 4: exact fp32 rescore, wave-per-row, div hoisted out of the
//      k-loop (1 div/candidate); wave-parallel scan fallback ----
__global__ __launch_bounds__(1024) void finalize_kernel(
    const int* __restrict__ cnt, const u16* __restrict__ cand,
    const float* __restrict__ x, const float* __restrict__ es,
    const float* __restrict__ cu, const float* __restrict__ e2f,
    float* __restrict__ out)
{
    int r = (blockIdx.x * 1024 + threadIdx.x) >> 6;  // one wave per row
    int lane = threadIdx.x & 63;
    int b = r >> 12, t = r & 4095;
    int n = cnt[r];

    float xv[4];
    #pragma unroll
    for (int j = 0; j < 4; j++)
        xv[j] = x[((size_t)b * D_ + lane + j * 64) * T_ + t];

    float best_s = 3.4e38f; int best_i = 0x7FFFFFFF;
    if (n <= CAP) {
        for (int p = 0; p < n; p++) {
            int c = (int)cand[(size_t)r * CAP + p];
            float partial = 0.f;
            #pragma unroll
            for (int j = 0; j < 4; j++)
                partial = fmaf(xv[j], es[(size_t)c * SEM_DIM + lane + j * 64], partial);
            #pragma unroll
            for (int m = 32; m >= 1; m >>= 1) partial += __shfl_xor(partial, m);
            float sc = fmaf(-2.0f / fmaxf(cu[c], EPSV), partial, e2f[c]);
            if (sc < best_s || (sc == best_s && c < best_i)) { best_s = sc; best_i = c; }
        }
    } else {
        // overflow fallback: exact wave-parallel scan of all codes
        for (int c = 0; c < CODEBOOK; c++) {
            float partial = 0.f;
            #pragma unroll
            for (int j = 0; j < 4; j++)
                partial = fmaf(xv[j], es[(size_t)c * SEM_DIM + lane + j * 64], partial);
            #pragma unroll
            for (int m = 32; m >= 1; m <<= 1) partial += __shfl_xor(partial, m);
            float sc = fmaf(-2.0f / fmaxf(cu[c], EPSV), partial, e2f[c]);
            if (sc < best_s) { best_s = sc; best_i = c; }
        }
    }
    if (lane == 0) out[(size_t)b * NCH * T_ + t] = (float)best_i;
}

// ---- kernel 5: fused tail — FSQ codes + ac recon (blocks [0,4608)) and
//      sem recon gather (blocks [4608,5120)) ----
__global__ __launch_bounds__(256) void tail_kernel(
    const float* __restrict__ x, const float* __restrict__ es,
    const float* __restrict__ cu, float* __restrict__ out)
{
    int bid = blockIdx.x;
    if (bid < 4608) {
        // FSQ: ac codes + ac recon
        int e = bid * 256 + threadIdx.x;
        int t = e & 4095;
        int rest = e >> 12;
        int j = rest % 36;
        int b = rest / 36;
        float v = x[(size_t)b * D_ * T_ + (size_t)(SEM_DIM + j) * T_ + t];
        float a = tanhf(v);
        float code = rintf((a + 1.0f) * 10.0f);
        out[(size_t)b * NCH * T_ + (size_t)(1 + j) * T_ + t] = code;
        out[RECON_OFF + (size_t)b * D_ * T_ + (size_t)(SEM_DIM + j) * T_ + t]
            = code * 0.1f - 1.0f;
    } else {
        // gather: sem recon
        int gb = bid - 4608;                  // 0..511
        int b  = gb >> 6;
        int tc = gb & 63;
        int t  = tc * 64 + (threadIdx.x & 63);
        int w  = threadIdx.x >> 6;

        int c = (int)out[(size_t)b * NCH * T_ + t];
        float denom = fmaxf(cu[c], EPSV);
        const float* erow = es + (size_t)c * SEM_DIM;
        float* orow = out + RECON_OFF + (size_t)b * D_ * T_ + t;

        #pragma unroll
        for (int i = 0; i < 16; i++) {
            int d = w * 64 + i * 4;
            float4 ev = *(const float4*)(erow + d);
            orow[(size_t)(d + 0) * T_] = ev.x / denom;
            orow[(size_t)(d + 1) * T_] = ev.y / denom;
            orow[(size_t)(d + 2) * T_] = ev.z / denom;
            orow[(size_t)(d + 3) * T_] = ev.w / denom;
        }
    }
}

extern "C" void kernel_launch(void* const* d_in, const int* in_sizes, int n_in,
                              void* d_out, int out_size, void* d_ws, size_t ws_size,
                              hipStream_t stream)
{
    const float* x  = (const float*)d_in[0];
    const float* es = (const float*)d_in[1];
    const float* cu = (const float*)d_in[2];
    float* out = (float*)d_out;

    u16*   Xt   = (u16*)(out + OFF_XT);
    u16*   Et   = (u16*)(out + OFF_ET);
    float* e2f  = out + OFF_E2G;
    float* gf   = out + OFF_E2G + 8192;
    float* x2   = out + OFF_X2;
    int*   cnt  = (int*)(out + OFF_CNT);
    u16*   cand = (u16*)(out + OFF_CAND);

    prep_emb_kernel<<<CODEBOOK, 256, 0, stream>>>(es, cu, Et, e2f, gf, cnt, x2);
    prep_x_kernel<<<B_ * 64 * 4, 256, 0, stream>>>(x, Xt, x2);

    gemm_emit_kernel<<<(ROWS / GBM) * NSP, 512, 0, stream>>>(
        Xt, Et, e2f, gf, x2, cnt, cand);

    finalize_kernel<<<ROWS / 16, 1024, 0, stream>>>(cnt, cand, x, es, cu, e2f, out);

    tail_kernel<<<5120, 256, 0, stream>>>(x, es, cu, out);
}